// Round 6
// baseline (944.633 us; speedup 1.0000x reference)
//
#include <hip/hip_runtime.h>
#include <hip/hip_bf16.h>
#include <stdint.h>

#define INPUT_DIM 1024
#define PRED_LEN 96
#define HIDDEN 512
#define BATCH 4096
#define W1_ROWS 1032  // INPUT_DIM + DAY_EMB

typedef __attribute__((ext_vector_type(8))) short bf16x8;
typedef __attribute__((ext_vector_type(4))) float floatx4;

__device__ __forceinline__ unsigned short f32_to_bf16_rne(float f) {
    union { float f; unsigned int u; } v; v.f = f;
    unsigned int u = v.u;
    unsigned int r = u + 0x7fffu + ((u >> 16) & 1u);
    return (unsigned short)(r >> 16);
}

__device__ __forceinline__ void async_copy16(const void* g, void* l) {
    __builtin_amdgcn_global_load_lds(
        (const __attribute__((address_space(1))) unsigned int*)g,
        (__attribute__((address_space(3))) unsigned int*)l, 16, 0, 0);
}

// ------------------------------------------------- convert x -> A' fragment layout
// A'[mt(32)][kt(16)][kk(2)][m(128)][ke(32)] bf16: each MFMA A-fragment load
// (16 rows x 32 k for one kk) is a CONTIGUOUS aligned 1 KB run -> one fully
// coalesced global_load_dwordx4 per fragment, no LDS staging for A at all.
__global__ void convert_x_kernel(const float* __restrict__ x,
                                 unsigned short* __restrict__ xa) {
    int g = (blockIdx.x * 256 + threadIdx.x) * 4;
    float4 v = *reinterpret_cast<const float4*>(x + g);
    ushort4 o;
    o.x = f32_to_bf16_rne(v.x);
    o.y = f32_to_bf16_rne(v.y);
    o.z = f32_to_bf16_rne(v.z);
    o.w = f32_to_bf16_rne(v.w);
    int mg = g >> 10;          // batch row
    int k  = g & 1023;
    int mt = mg >> 7, m = mg & 127;
    int kt = k >> 6, kk = (k >> 5) & 1, ke = k & 31;
    size_t idx = (size_t)mt * 131072 + (kt * 2 + kk) * 4096 + m * 32 + ke;
    *reinterpret_cast<ushort4*>(xa + idx) = o;
}

// ------------------------------------------- transpose+convert W1x -> (p,n,k)
// (validated round 5) 4x4 register-block transpose, chunk16-XOR-swizzled tile.
__global__ void transpose_w1_kernel(const float* __restrict__ W1,
                                    unsigned short* __restrict__ W1t) {
    __shared__ unsigned short tile[64 * 64];  // [n][k], swizzled chunks
    int bid = blockIdx.x;
    int nt = bid & 7;          // n tile (8 x 64)
    int kt = (bid >> 3) & 15;  // k tile (16 x 64)
    int p  = bid >> 7;
    int t  = threadIdx.x;
    const float* src = W1 + (size_t)p * W1_ROWS * HIDDEN;
    const int k0 = kt * 64, n0 = nt * 64;

    const int tn = t & 15;    // n-group
    const int tk = t >> 4;    // k-group 0..15
    float4 v[4];
    #pragma unroll
    for (int i = 0; i < 4; ++i)
        v[i] = *reinterpret_cast<const float4*>(src + (size_t)(k0 + 4 * tk + i) * HIDDEN + n0 + 4 * tn);
    const int slot1 = ((tk >> 2) ^ (tn & 3)) * 16 + (tk & 3) * 4;
    {
        ushort4 w0, w1, w2, w3;
        w0.x = f32_to_bf16_rne(v[0].x); w0.y = f32_to_bf16_rne(v[1].x);
        w0.z = f32_to_bf16_rne(v[2].x); w0.w = f32_to_bf16_rne(v[3].x);
        w1.x = f32_to_bf16_rne(v[0].y); w1.y = f32_to_bf16_rne(v[1].y);
        w1.z = f32_to_bf16_rne(v[2].y); w1.w = f32_to_bf16_rne(v[3].y);
        w2.x = f32_to_bf16_rne(v[0].z); w2.y = f32_to_bf16_rne(v[1].z);
        w2.z = f32_to_bf16_rne(v[2].z); w2.w = f32_to_bf16_rne(v[3].z);
        w3.x = f32_to_bf16_rne(v[0].w); w3.y = f32_to_bf16_rne(v[1].w);
        w3.z = f32_to_bf16_rne(v[2].w); w3.w = f32_to_bf16_rne(v[3].w);
        *reinterpret_cast<ushort4*>(tile + (4 * tn + 0) * 64 + slot1) = w0;
        *reinterpret_cast<ushort4*>(tile + (4 * tn + 1) * 64 + slot1) = w1;
        *reinterpret_cast<ushort4*>(tile + (4 * tn + 2) * 64 + slot1) = w2;
        *reinterpret_cast<ushort4*>(tile + (4 * tn + 3) * 64 + slot1) = w3;
    }
    __syncthreads();

    const int nr = t >> 2;
    const int q  = t & 3;
    const int slot2 = (q ^ ((nr >> 2) & 3)) * 16;
    uint4 a = *reinterpret_cast<const uint4*>(tile + nr * 64 + slot2);
    uint4 b = *reinterpret_cast<const uint4*>(tile + nr * 64 + slot2 + 8);
    size_t dst = ((size_t)p * HIDDEN + n0 + nr) * 1024 + k0 + q * 16;
    *reinterpret_cast<uint4*>(W1t + dst)     = a;
    *reinterpret_cast<uint4*>(W1t + dst + 8) = b;
}

// -------------------------------------------------- exact f32 bias precompute
__global__ void bias_kernel(const float* __restrict__ W1,
                            const float* __restrict__ day_emb,
                            const float* __restrict__ b1,
                            float* __restrict__ bias) {
    int p = blockIdx.x;
    int h = threadIdx.x;  // 512 threads
    const float* W1e = W1 + ((size_t)p * W1_ROWS + INPUT_DIM) * HIDDEN;
    float acc = b1[p * HIDDEN + h];
    #pragma unroll
    for (int e = 0; e < 8; ++e)
        acc += day_emb[p * 8 + e] * W1e[(size_t)e * HIDDEN + h];
    bias[p * HIDDEN + h] = acc;
}

// ------------------------------------- fused GEMM + relu + W2 reduction + b2
// Round-6: A bypasses LDS entirely — af fragments come from the A' layout as
// coalesced 1 KB global loads (L3-resident 8.4 MB; wj-pair waves share af
// lines via L1). LDS stages ONLY B (reads halve: r5 showed LDS port at 84%
// = the saturated pipe). B keeps the XOR swizzle (0 conflicts, r2-r5).
// (256,3): ~170-reg cap, zero spill (r5: WRITE_SIZE 3.8 MB).
__global__ void __launch_bounds__(256, 3)
mlp_head_kernel(const unsigned short* __restrict__ xa,   // A' bf16 (see convert_x)
                const unsigned short* __restrict__ W1t,  // 96x512x1024 bf16 (N-major)
                const float* __restrict__ bias,          // 96x512 f32
                const float* __restrict__ W2,            // 96x512 f32
                const float* __restrict__ b2,            // 96 f32
                float* __restrict__ out)                 // 4096x96 f32
{
    __shared__ unsigned short Bs[128 * 64];
    __shared__ float w2s[HIDDEN];
    __shared__ float biass[HIDDEN];
    __shared__ float red[2][128];

    const int mt   = blockIdx.x;  // 0..31 batch tile
    const int p    = blockIdx.y;  // 0..95
    const int t    = threadIdx.x;
    const int lane = t & 63;
    const int w    = t >> 6;
    const int wi   = w >> 1;      // row half (64)
    const int wj   = w & 1;       // col half (64)
    const int l15  = lane & 15;
    const int quad = lane >> 4;
    const int xl   = l15 & 7;     // swizzle key for fragment reads

    // B staging constants: thread stages LDS slot (row, t&7) with global chunk
    // (t&7)^(row&7); row = c*32 + (t>>3)
    const int t3    = t >> 3;                    // 0..31
    const int skc   = ((t & 7) ^ (t3 & 7)) * 8;  // swizzled k-offset (elems)
    const int ldsq8 = t * 8;                     // per-c LDS offset adds 2048

    for (int i = t; i < HIDDEN; i += 256) {
        w2s[i]   = W2[p * HIDDEN + i];
        biass[i] = bias[p * HIDDEN + i];
    }

    const int m0 = mt * 128;
    // per-lane A' base: fragment (kt,kk,i) adds (kt*2+kk)*4096 + i*512
    const unsigned short* pA = xa + (size_t)mt * 131072
                              + (wi * 64 + l15) * 32 + quad * 8;
    const unsigned short* bg = W1t + (size_t)p * HIDDEN * 1024
                              + (size_t)t3 * 1024 + skc;

    float partial[4][4];
    #pragma unroll
    for (int i = 0; i < 4; ++i)
        #pragma unroll
        for (int r = 0; r < 4; ++r) partial[i][r] = 0.f;

    for (int nt = 0; nt < 4; ++nt) {
        floatx4 acc[4][4];
        #pragma unroll
        for (int i = 0; i < 4; ++i)
            #pragma unroll
            for (int j = 0; j < 4; ++j)
                acc[i][j] = (floatx4){0.f, 0.f, 0.f, 0.f};

        const size_t bn = (size_t)nt * 128 * 1024;  // n-tile offset in W1t

        for (int k0 = 0; k0 < 1024; k0 += 64) {
            __syncthreads();  // prior K-step's Bs reads complete
            #pragma unroll
            for (int c = 0; c < 4; ++c)
                async_copy16(bg + bn + (size_t)c * 32 * 1024 + k0, Bs + ldsq8 + c * 2048);
            __syncthreads();  // Bs staged
            const int ktk = (k0 >> 6) * 2;
            #pragma unroll
            for (int kk = 0; kk < 2; ++kk) {
                const int slot = (kk * 4 + quad) ^ xl;  // swizzled chunk position
                const unsigned short* pAk = pA + (size_t)(ktk + kk) * 4096;
                bf16x8 af[4], bfr[4];
                #pragma unroll
                for (int i = 0; i < 4; ++i)
                    af[i] = *reinterpret_cast<const bf16x8*>(pAk + i * 512);
                #pragma unroll
                for (int j = 0; j < 4; ++j) {
                    int n = wj * 64 + j * 16 + l15;
                    bfr[j] = *reinterpret_cast<const bf16x8*>(Bs + n * 64 + slot * 8);
                }
                #pragma unroll
                for (int i = 0; i < 4; ++i)
                    #pragma unroll
                    for (int j = 0; j < 4; ++j)
                        acc[i][j] = __builtin_amdgcn_mfma_f32_16x16x32_bf16(
                            af[i], bfr[j], acc[i][j], 0, 0, 0);
            }
        }

        // epilogue for this n-tile: bias + relu + weight by W2, fold into partials
        const int n0 = nt * 128;
        #pragma unroll
        for (int j = 0; j < 4; ++j) {
            int c = n0 + wj * 64 + j * 16 + l15;  // C layout: col = lane&15
            float w2v = w2s[c];
            float bv  = biass[c];
            #pragma unroll
            for (int i = 0; i < 4; ++i)
                #pragma unroll
                for (int r = 0; r < 4; ++r) {
                    float hv = acc[i][j][r] + bv;
                    hv = hv > 0.f ? hv : 0.f;
                    partial[i][r] += hv * w2v;
                }
        }
    }

    // reduce over columns: 16 lanes of each quad hold distinct cols of same rows
    #pragma unroll
    for (int i = 0; i < 4; ++i)
        #pragma unroll
        for (int r = 0; r < 4; ++r) {
            float v = partial[i][r];
            v += __shfl_xor(v, 1);
            v += __shfl_xor(v, 2);
            v += __shfl_xor(v, 4);
            v += __shfl_xor(v, 8);
            partial[i][r] = v;
        }

    if (l15 == 0) {
        #pragma unroll
        for (int i = 0; i < 4; ++i)
            #pragma unroll
            for (int r = 0; r < 4; ++r) {
                int row = wi * 64 + i * 16 + quad * 4 + r;  // C layout: row = quad*4+reg
                red[wj][row] = partial[i][r];
            }
    }
    __syncthreads();
    if (t < 128) {
        float v = red[0][t] + red[1][t] + b2[p];
        out[(size_t)(m0 + t) * PRED_LEN + p] = v;
    }
}

// ---------------------------------------------------------------------------
extern "C" void kernel_launch(void* const* d_in, const int* in_sizes, int n_in,
                              void* d_out, int out_size, void* d_ws, size_t ws_size,
                              hipStream_t stream) {
    const float* x       = (const float*)d_in[0];
    const float* day_emb = (const float*)d_in[1];
    const float* W1      = (const float*)d_in[2];
    const float* b1      = (const float*)d_in[3];
    const float* W2      = (const float*)d_in[4];
    const float* b2      = (const float*)d_in[5];
    float* out = (float*)d_out;

    const size_t xa_bytes  = (size_t)BATCH * INPUT_DIM * 2;             // 8,388,608
    const size_t w1t_bytes = (size_t)PRED_LEN * HIDDEN * INPUT_DIM * 2; // 100,663,296
    const size_t bias_bytes = (size_t)PRED_LEN * HIDDEN * 4;            // 196,608
    if (ws_size < xa_bytes + w1t_bytes + bias_bytes) return;

    unsigned short* xa  = (unsigned short*)d_ws;
    unsigned short* w1t = (unsigned short*)((char*)d_ws + xa_bytes);
    float* biasp        = (float*)((char*)d_ws + xa_bytes + w1t_bytes);

    convert_x_kernel<<<(BATCH * INPUT_DIM) / (256 * 4), 256, 0, stream>>>(x, xa);
    transpose_w1_kernel<<<PRED_LEN * 16 * 8, 256, 0, stream>>>(W1, w1t);
    bias_kernel<<<PRED_LEN, HIDDEN, 0, stream>>>(W1, day_emb, b1, biasp);

    dim3 grid(BATCH / 128, PRED_LEN);
    mlp_head_kernel<<<grid, 256, 0, stream>>>(xa, w1t, biasp, W2, b2, out);
}